// Round 1
// baseline (656.592 us; speedup 1.0000x reference)
//
#include <hip/hip_runtime.h>
#include <hip/hip_bf16.h>

// GroupedEmbeddingBag: T=8 tables [V=100000, D=128] fp32, B=4096 bags/table,
// N=204800 jagged values/table. out[b, t*D+d] = sum_{i in [offs[t][b], offs[t][b+1])}
// tables[t][values[t][i]][d] * psw[t][i].
//
// One 128-thread block per (t, b): lane d owns column d. Row gathers are
// 512B contiguous+coalesced. Grid ordered t*B+b so resident blocks share one
// table's working set in L2/L3 (row reuse ~2x). Pooling loop unrolled x2 for
// two independent row-gathers in flight per block.

namespace {
constexpr int T = 8;
constexpr int V = 100000;
constexpr int D = 128;
constexpr int B = 4096;
constexpr int N = 204800;
}

__global__ __launch_bounds__(128) void grouped_ebag_kernel(
    const float* __restrict__ tables,   // [T, V, D]
    const int* __restrict__ values,     // [T, N]
    const int* __restrict__ offsets,    // [T, B+1]
    const float* __restrict__ psw,      // [T, N]
    float* __restrict__ out)            // [B, T*D]
{
    const int bag = blockIdx.x;         // 0 .. T*B-1, ordered (t, b)
    const int t = bag >> 12;            // B = 4096
    const int b = bag & (B - 1);
    const int d = threadIdx.x;          // 0..127

    const int start = offsets[t * (B + 1) + b];
    const int end   = offsets[t * (B + 1) + b + 1];

    const float* __restrict__ tab  = tables + (size_t)t * V * D;
    const int*   __restrict__ vals = values + (size_t)t * N;
    const float* __restrict__ w    = psw    + (size_t)t * N;

    float acc0 = 0.0f;
    float acc1 = 0.0f;

    int i = start;
    for (; i + 1 < end; i += 2) {
        // Two independent row gathers in flight (latency hiding).
        const int   v0 = vals[i];
        const int   v1 = vals[i + 1];
        const float w0 = w[i];
        const float w1 = w[i + 1];
        const float e0 = tab[(size_t)v0 * D + d];
        const float e1 = tab[(size_t)v1 * D + d];
        acc0 = fmaf(e0, w0, acc0);
        acc1 = fmaf(e1, w1, acc1);
    }
    if (i < end) {
        const int   v0 = vals[i];
        const float w0 = w[i];
        acc0 = fmaf(tab[(size_t)v0 * D + d], w0, acc0);
    }

    out[(size_t)b * (T * D) + t * D + d] = acc0 + acc1;
}

extern "C" void kernel_launch(void* const* d_in, const int* in_sizes, int n_in,
                              void* d_out, int out_size, void* d_ws, size_t ws_size,
                              hipStream_t stream) {
    const float* tables  = (const float*)d_in[0];
    const int*   values  = (const int*)d_in[1];
    const int*   offsets = (const int*)d_in[2];
    const float* psw     = (const float*)d_in[3];
    float*       out     = (float*)d_out;

    dim3 grid(T * B);
    dim3 block(D);
    grouped_ebag_kernel<<<grid, block, 0, stream>>>(tables, values, offsets, psw, out);
}

// Round 2
// 572.086 us; speedup vs baseline: 1.1477x; 1.1477x over previous
//
#include <hip/hip_runtime.h>
#include <hip/hip_bf16.h>

// GroupedEmbeddingBag: T=8 tables [V=100000, D=128] fp32, B=4096 bags/table.
// out[b, t*D+d] = sum_{i in [offs[t][b], offs[t][b+1])} tables[t][values[t][i]][d] * psw[t][i]
//
// R1: latency-bound fix. One WAVE per bag (4 bags / 256-thread block).
//  - lane = (half = row parity, c4 = float4 col block): each row gather is
//    32 lanes x 16B = 512B contiguous; one wave-load covers 2 rows.
//  - 8 rows (4 pair-loads) in flight per wave, indices/weights software-
//    pipelined one group ahead -> gathers never stall on index fetch.
//  - halves combined with shfl_xor(32); lanes 0-31 store float4 (512B/bag).

namespace {
constexpr int T = 8;
constexpr int V = 100000;
constexpr int D = 128;
constexpr int B = 4096;
constexpr int N = 204800;
}

__global__ __launch_bounds__(256) void grouped_ebag_kernel(
    const float* __restrict__ tables,   // [T, V, D]
    const int* __restrict__ values,     // [T, N]
    const int* __restrict__ offsets,    // [T, B+1]
    const float* __restrict__ psw,      // [T, N]
    float* __restrict__ out)            // [B, T*D]
{
    const int wave = threadIdx.x >> 6;            // 0..3
    const int lane = threadIdx.x & 63;
    const int bag  = (blockIdx.x << 2) + wave;    // 0 .. T*B-1, (t, b) ordered
    const int t = bag >> 12;                      // B = 4096
    const int b = bag & (B - 1);
    const int half = lane >> 5;                   // row parity within a pair
    const int c4   = lane & 31;                   // float4 column block

    const int start = offsets[t * (B + 1) + b];
    const int end   = offsets[t * (B + 1) + b + 1];

    const float* __restrict__ tab  = tables + (size_t)t * (V * D);
    const int*   __restrict__ vals = values + (size_t)t * N;
    const float* __restrict__ wgt  = psw    + (size_t)t * N;

    float4 acc = make_float4(0.f, 0.f, 0.f, 0.f);

    const int len  = end - start;
    const int ngrp = len >> 3;                    // groups of 8 rows

    // Software pipeline: indices/weights for group g+1 load while group g gathers.
    int   v[4];
    float wv[4];
    if (ngrp > 0) {
#pragma unroll
        for (int j = 0; j < 4; ++j) {
            v[j]  = vals[start + 2 * j + half];
            wv[j] = wgt [start + 2 * j + half];
        }
    }

    int i = start;
    for (int g = 0; g < ngrp; ++g) {
        int   vn[4] = {0, 0, 0, 0};
        float wn[4] = {0.f, 0.f, 0.f, 0.f};
        const int inext = i + 8;
        if (g + 1 < ngrp) {
#pragma unroll
            for (int j = 0; j < 4; ++j) {
                vn[j] = vals[inext + 2 * j + half];
                wn[j] = wgt [inext + 2 * j + half];
            }
        }
#pragma unroll
        for (int j = 0; j < 4; ++j) {
            const float4 e = *(const float4*)(tab + (size_t)v[j] * D + c4 * 4);
            acc.x = fmaf(e.x, wv[j], acc.x);
            acc.y = fmaf(e.y, wv[j], acc.y);
            acc.z = fmaf(e.z, wv[j], acc.z);
            acc.w = fmaf(e.w, wv[j], acc.w);
        }
#pragma unroll
        for (int j = 0; j < 4; ++j) { v[j] = vn[j]; wv[j] = wn[j]; }
        i = inext;
    }

    // Remainder: pairs of rows (both halves active).
    for (; i + 2 <= end; i += 2) {
        const int   vv = vals[i + half];
        const float ww = wgt [i + half];
        const float4 e = *(const float4*)(tab + (size_t)vv * D + c4 * 4);
        acc.x = fmaf(e.x, ww, acc.x);
        acc.y = fmaf(e.y, ww, acc.y);
        acc.z = fmaf(e.z, ww, acc.z);
        acc.w = fmaf(e.w, ww, acc.w);
    }
    // Last odd row: lanes 0-31 only.
    if (i < end && half == 0) {
        const int   vv = vals[i];
        const float ww = wgt [i];
        const float4 e = *(const float4*)(tab + (size_t)vv * D + c4 * 4);
        acc.x = fmaf(e.x, ww, acc.x);
        acc.y = fmaf(e.y, ww, acc.y);
        acc.z = fmaf(e.z, ww, acc.z);
        acc.w = fmaf(e.w, ww, acc.w);
    }

    // Combine even/odd row halves across the wave.
    acc.x += __shfl_xor(acc.x, 32);
    acc.y += __shfl_xor(acc.y, 32);
    acc.z += __shfl_xor(acc.z, 32);
    acc.w += __shfl_xor(acc.w, 32);

    if (half == 0) {
        *(float4*)(out + (size_t)b * (T * D) + t * D + c4 * 4) = acc;
    }
}

extern "C" void kernel_launch(void* const* d_in, const int* in_sizes, int n_in,
                              void* d_out, int out_size, void* d_ws, size_t ws_size,
                              hipStream_t stream) {
    const float* tables  = (const float*)d_in[0];
    const int*   values  = (const int*)d_in[1];
    const int*   offsets = (const int*)d_in[2];
    const float* psw     = (const float*)d_in[3];
    float*       out     = (float*)d_out;

    dim3 grid((T * B) / 4);   // 4 bags (waves) per 256-thread block
    dim3 block(256);
    grouped_ebag_kernel<<<grid, block, 0, stream>>>(tables, values, offsets, psw, out);
}